// Round 19
// baseline (207.170 us; speedup 1.0000x reference)
//
#include <hip/hip_runtime.h>

#define D_MODEL 1024
#define T_SEQ   2048
#define BATCH   2
#define HEADS   16
#define DKH     64
#define M_ROWS  (BATCH*T_SEQ)   // 4096
#define OUT0_SZ (M_ROWS*D_MODEL)  // 4194304
#define PSTR    2060              // P-buffer row stride in bf16 (4120B)
#define HSTRIDE (T_SEQ*DKH)       // 131072 elems per head

typedef short bf16x8 __attribute__((ext_vector_type(8)));
typedef float f32x4  __attribute__((ext_vector_type(4)));
typedef unsigned short u16x4 __attribute__((ext_vector_type(4)));

__device__ __forceinline__ unsigned short f2bf(float f) {
    unsigned u = __builtin_bit_cast(unsigned, f);
    u = (u + 0x7fffu + ((u >> 16) & 1u)) >> 16;
    return (unsigned short)u;
}

__device__ __forceinline__ void gload_lds16(const void* g, void* l) {
    __builtin_amdgcn_global_load_lds(
        (const __attribute__((address_space(1))) void*)g,
        (__attribute__((address_space(3))) void*)l, 16, 0, 0);
}

// ---------------- fp32 -> bf16 convert: x + all 4 weights, ONE launch ----------------
__global__ __launch_bounds__(256) void k_cvt_all(const float* __restrict__ x,
                                                 const float* __restrict__ w0,
                                                 const float* __restrict__ w1,
                                                 const float* __restrict__ w2,
                                                 const float* __restrict__ w3,
                                                 unsigned short* __restrict__ xb,
                                                 unsigned short* __restrict__ wb) {
    int blk = blockIdx.x;
    const float* src;
    unsigned short* dst;
    int i;
    if (blk < 4096) {
        src = x; dst = xb; i = blk * 256 + threadIdx.x;
    } else {
        int k = (blk - 4096) >> 10;
        src = (k == 0) ? w0 : (k == 1) ? w1 : (k == 2) ? w2 : w3;
        dst = wb + (size_t)k * 1048576;
        i = ((blk - 4096) & 1023) * 256 + threadIdx.x;
    }
    float4 v = reinterpret_cast<const float4*>(src)[i];
    ushort4 o;
    o.x = f2bf(v.x); o.y = f2bf(v.y); o.z = f2bf(v.z); o.w = f2bf(v.w);
    reinterpret_cast<ushort4*>(dst)[i] = o;
}

// ---------------- shared 128x256 GEMM core (C = A * W^T), K = 1024 ----------------
// A-tile 128 rows, B-tile 256 rows (of W), BK=64. 4 waves: wave (wm,wn) owns
// 64x128 output -> acc[4][8]. Same XOR-swizzled LDS scheme as before.
template<int NROWS>
__device__ __forceinline__ void stage_tile(const unsigned short* __restrict__ g,
                                           int r0, int k0, unsigned short* s, int tid) {
#pragma unroll
    for (int it = 0; it < NROWS / 32; ++it) {
        int row   = (tid >> 3) + it * 32;
        int kb_sw = (tid & 7) << 4;
        int kb    = kb_sw ^ ((row & 7) << 4);
        const unsigned short* gp = g + (size_t)(r0 + row) * D_MODEL + k0 + (kb >> 1);
        gload_lds16(gp, s + (tid >> 6) * 512 + it * 2048);
    }
}

__device__ __forceinline__ bf16x8 ld_frag(const unsigned short* s, int row, int kbyte) {
    int off = (row << 7) + (kbyte ^ ((row & 7) << 4));
    return *reinterpret_cast<const bf16x8*>(reinterpret_cast<const char*>(s) + off);
}

__device__ __forceinline__ void gemm_core_256(const unsigned short* __restrict__ A,
                                              const unsigned short* __restrict__ W,
                                              unsigned short* sA, unsigned short* sB,
                                              int m0, int n0, f32x4 (&acc)[4][8], int tid) {
    int lane = tid & 63, lr = lane & 15, lg = lane >> 4;
    int wm = tid >> 7, wn = (tid >> 6) & 1;
#pragma unroll 1
    for (int k0 = 0; k0 < D_MODEL; k0 += 64) {
        stage_tile<128>(A, m0, k0, sA, tid);
        stage_tile<256>(W, n0, k0, sB, tid);
        __syncthreads();
#pragma unroll
        for (int kk = 0; kk < 2; ++kk) {
            bf16x8 a[4], b[8];
#pragma unroll
            for (int f = 0; f < 4; ++f)
                a[f] = ld_frag(sA, wm * 64 + f * 16 + lr, kk * 64 + lg * 16);
#pragma unroll
            for (int f = 0; f < 8; ++f)
                b[f] = ld_frag(sB, wn * 128 + f * 16 + lr, kk * 64 + lg * 16);
#pragma unroll
            for (int i = 0; i < 4; ++i)
#pragma unroll
                for (int j = 0; j < 8; ++j)
                    acc[i][j] = __builtin_amdgcn_mfma_f32_16x16x32_bf16(a[i], b[j], acc[i][j], 0, 0, 0);
        }
        __syncthreads();
    }
}

// ---------------- QKV projection (Q/K/V all written in MFMA-fragment order) ----------------
__global__ __launch_bounds__(256) void k_gemm_qkv(const unsigned short* __restrict__ Xb,
                                                  const unsigned short* __restrict__ Wb,
                                                  const float* __restrict__ bq,
                                                  const float* __restrict__ bk,
                                                  const float* __restrict__ bv,
                                                  unsigned short* __restrict__ Qb,
                                                  unsigned short* __restrict__ Kb,
                                                  unsigned short* __restrict__ Vt) {
    __shared__ unsigned short sA[128 * 64];   // 16 KB
    __shared__ unsigned short sB[256 * 64];   // 32 KB
    int tid = threadIdx.x;
    int m0 = blockIdx.x * 128, n0 = blockIdx.y * 256, z = blockIdx.z;
    const unsigned short* W = Wb + (size_t)z * (D_MODEL * D_MODEL);
    const float* bias = (z == 0) ? bq : (z == 1) ? bk : bv;
    f32x4 acc[4][8];
#pragma unroll
    for (int i = 0; i < 4; ++i)
#pragma unroll
        for (int j = 0; j < 8; ++j) acc[i][j] = (f32x4){0.f, 0.f, 0.f, 0.f};

    gemm_core_256(Xb, W, sA, sB, m0, n0, acc, tid);

    int lane = tid & 63, lr = lane & 15, lg = lane >> 4;
    int wm = tid >> 7, wn = (tid >> 6) & 1;
    float scl = (z == 0) ? 0.125f : 1.0f;   // fold 1/sqrt(64) into Q
#pragma unroll
    for (int i = 0; i < 4; ++i) {
#pragma unroll
        for (int j = 0; j < 8; ++j) {
            int col = n0 + wn * 128 + j * 16 + lr;      // n = h*64 + d
            float bb = bias[col];
            int h = col >> 6, d = col & 63;
#pragma unroll
            for (int q = 0; q < 4; ++q) {
                int row = m0 + wm * 64 + i * 16 + lg * 4 + q;  // b*T + t
                int b = row >> 11, tt = row & 2047;
                float v = (acc[i][j][q] + bb) * scl;
                unsigned short h16 = f2bf(v);
                size_t bh = (size_t)b * HEADS + h;
                if (z == 2) {
                    int st = tt >> 6, ks = (tt >> 5) & 1, lgv = (tt >> 3) & 3, e = tt & 7;
                    Vt[bh * HSTRIDE + st * 4096 + ks * 2048 + lgv * 512 + d * 8 + e] = h16;
                } else if (z == 0) {
                    int ch = tt >> 4, t_in = tt & 15, kk2 = d >> 5, lg8 = (d >> 3) & 3, e = d & 7;
                    Qb[bh * HSTRIDE + ch * 1024 + kk2 * 512 + lg8 * 128 + t_in * 8 + e] = h16;
                } else {
                    int st = tt >> 6, s_in = tt & 63, kk2 = d >> 5, lg8 = (d >> 3) & 3, e = d & 7;
                    Kb[bh * HSTRIDE + st * 4096 + kk2 * 2048 + lg8 * 512 + s_in * 8 + e] = h16;
                }
            }
        }
    }
}

// ---------------- output projection ----------------
__global__ __launch_bounds__(256) void k_gemm_o(const unsigned short* __restrict__ Ctx,
                                                const unsigned short* __restrict__ Wo,
                                                const float* __restrict__ bo,
                                                float* __restrict__ out) {
    __shared__ unsigned short sA[128 * 64];
    __shared__ unsigned short sB[256 * 64];
    int tid = threadIdx.x;
    int m0 = blockIdx.x * 128, n0 = blockIdx.y * 256;
    f32x4 acc[4][8];
#pragma unroll
    for (int i = 0; i < 4; ++i)
#pragma unroll
        for (int j = 0; j < 8; ++j) acc[i][j] = (f32x4){0.f, 0.f, 0.f, 0.f};

    gemm_core_256(Ctx, Wo, sA, sB, m0, n0, acc, tid);

    int lane = tid & 63, lr = lane & 15, lg = lane >> 4;
    int wm = tid >> 7, wn = (tid >> 6) & 1;
#pragma unroll
    for (int i = 0; i < 4; ++i)
#pragma unroll
        for (int j = 0; j < 8; ++j) {
            int col = n0 + wn * 128 + j * 16 + lr;
            float bb = bo[col];
#pragma unroll
            for (int q = 0; q < 4; ++q) {
                int row = m0 + wm * 64 + i * 16 + lg * 4 + q;
                out[(size_t)row * D_MODEL + col] = acc[i][j][q] + bb;
            }
        }
}

// ---------------- fused causal attention: coalesced fragment loads + NT stores ----------------
__global__ __launch_bounds__(512) void k_attn(const unsigned short* __restrict__ Qb,
                                              const unsigned short* __restrict__ Kb,
                                              const unsigned short* __restrict__ Vt,
                                              float* __restrict__ Wout,
                                              unsigned short* __restrict__ Ctx) {
    __shared__ unsigned short P[16 * PSTR];   // 65,920 B
    __shared__ float l8[8][16];
    __shared__ float linv[16];
    int tid = threadIdx.x, w = tid >> 6, lane = tid & 63, lr = lane & 15, lg = lane >> 4;
    int bh = blockIdx.y;
    int b = bh >> 4, h = bh & 15;
    int chunk = (blockIdx.x * 53 + 17) & 127;  // decorrelating bijection
    int t0 = chunk * 16;
    int ntiles = (chunk >> 2) + 1;
    int q_row = t0 + lr;

    const unsigned short* Qh = Qb + (size_t)bh * HSTRIDE;
    const unsigned short* Kh = Kb + (size_t)bh * HSTRIDE;
    const unsigned short* Vh = Vt + (size_t)bh * HSTRIDE;
    float* Whead = Wout + (size_t)bh * T_SEQ * T_SEQ;

    bf16x8 qf[2];
#pragma unroll
    for (int kk = 0; kk < 2; ++kk)
        qf[kk] = *reinterpret_cast<const bf16x8*>(
            Qh + chunk * 1024 + kk * 512 + lg * 128 + lr * 8);

    // ---- phase A: QK^T once (tiles st%8==w), coalesced Kf fragment loads ----
    float lacc = 0.f;
    for (int st = w; st < ntiles; st += 8) {
        int s0 = st * 64;
        bool diag = (st == ntiles - 1);
#pragma unroll
        for (int cf = 0; cf < 4; ++cf) {
            f32x4 a = (f32x4){0.f, 0.f, 0.f, 0.f};
#pragma unroll
            for (int kk = 0; kk < 2; ++kk) {
                bf16x8 kf = *reinterpret_cast<const bf16x8*>(
                    Kh + st * 4096 + kk * 2048 + lg * 512 + (cf * 16 + lr) * 8);
                a = __builtin_amdgcn_mfma_f32_16x16x32_bf16(kf, qf[kk], a, 0, 0, 0);
            }
            u16x4 pb;
#pragma unroll
            for (int r = 0; r < 4; ++r) {
                int s = s0 + cf * 16 + lg * 4 + r;
                float p = (diag && s > q_row) ? 0.f : __expf(a[r] - 16.f);
                lacc += p;
                pb[r] = f2bf(p);
            }
            *reinterpret_cast<u16x4*>(&P[lr * PSTR + s0 + cf * 16 + lg * 4]) = pb;
        }
    }
    lacc += __shfl_xor(lacc, 16);
    lacc += __shfl_xor(lacc, 32);
    l8[w][lr] = lacc;
    __syncthreads();
    if (tid < 16) {
        float s = 0.f;
#pragma unroll
        for (int i = 0; i < 8; ++i) s += l8[i][tid];
        linv[tid] = 1.0f / s;
    }
    __syncthreads();

    if (w < 4) {
        // ===== waves 0-3: PV for d-quarter w over ALL tiles (coalesced Vf) + Ctx =====
        float invq = linv[lr];
        f32x4 of = (f32x4){0.f, 0.f, 0.f, 0.f};
        for (int st = 0; st < ntiles; ++st) {
            int s0 = st * 64;
#pragma unroll
            for (int ks = 0; ks < 2; ++ks) {
                bf16x8 pa = *reinterpret_cast<const bf16x8*>(&P[lr * PSTR + s0 + ks * 32 + lg * 8]);
                bf16x8 vf = *reinterpret_cast<const bf16x8*>(
                    Vh + st * 4096 + ks * 2048 + lg * 512 + (w * 16 + lr) * 8);
                of = __builtin_amdgcn_mfma_f32_16x16x32_bf16(vf, pa, of, 0, 0, 0);
            }
        }
        u16x4 c4;
#pragma unroll
        for (int r = 0; r < 4; ++r) c4[r] = f2bf(of[r] * invq);
        *reinterpret_cast<u16x4*>(
            &Ctx[((size_t)b * T_SEQ + q_row) * D_MODEL + h * DKH + w * 16 + lg * 4]) = c4;
    } else {
        // ===== waves 4-7: NT weight stores, rows (w-4)*4 .. +3, 8KB/row =====
        int vcols = ntiles * 64;
        int wq = w - 4;
#pragma unroll
        for (int rr = 0; rr < 4; ++rr) {
            int row = wq * 4 + rr;
            float invlr = linv[row];
            float* dst = Whead + (size_t)(t0 + row) * T_SEQ;
            const unsigned short* prow = &P[row * PSTR];
#pragma unroll 2
            for (int j = 0; j < 8; ++j) {
                int col = j * 256 + lane * 4;
                f32x4 v = (f32x4){0.f, 0.f, 0.f, 0.f};
                if (col < vcols) {
                    u16x4 pb = *reinterpret_cast<const u16x4*>(&prow[col]);
#pragma unroll
                    for (int r = 0; r < 4; ++r)
                        v[r] = __builtin_bit_cast(float, (unsigned)pb[r] << 16) * invlr;
                }
                __builtin_nontemporal_store(v, reinterpret_cast<f32x4*>(dst + col));
            }
        }
    }
}

extern "C" void kernel_launch(void* const* d_in, const int* in_sizes, int n_in,
                              void* d_out, int out_size, void* d_ws, size_t ws_size,
                              hipStream_t stream) {
    const float* x  = (const float*)d_in[0];
    const float* Wq = (const float*)d_in[1];
    const float* bq = (const float*)d_in[2];
    const float* Wk = (const float*)d_in[3];
    const float* bk = (const float*)d_in[4];
    const float* Wv = (const float*)d_in[5];
    const float* bv = (const float*)d_in[6];
    const float* Wo = (const float*)d_in[7];
    const float* bo = (const float*)d_in[8];
    float* out = (float*)d_out;

    char* ws = (char*)d_ws;
    unsigned short* Xb  = (unsigned short*)(ws);                 // 8 MB
    unsigned short* Wb  = (unsigned short*)(ws + 8388608);       // 8 MB (Wq,Wk,Wv,Wo)
    unsigned short* Qb  = (unsigned short*)(ws + 16777216);      // 8 MB
    unsigned short* Kb  = (unsigned short*)(ws + 25165824);      // 8 MB
    unsigned short* Vt  = (unsigned short*)(ws + 33554432);      // 8 MB
    unsigned short* Ctx = (unsigned short*)(ws + 41943040);      // 8 MB

    // fp32 -> bf16 (x + all weights, one launch)
    k_cvt_all<<<8192, 256, 0, stream>>>(x, Wq, Wk, Wv, Wo, Xb, Wb);

    // QKV projection: grid (M/128, N/256, 3)
    k_gemm_qkv<<<dim3(32, 4, 3), 256, 0, stream>>>(Xb, Wb, bq, bk, bv, Qb, Kb, Vt);

    // fused causal attention (coalesced fragment loads, NT streaming stores)
    k_attn<<<dim3(128, 32), 512, 0, stream>>>(Qb, Kb, Vt, out + OUT0_SZ, Ctx);

    // output projection: grid (M/128, N/256)
    k_gemm_o<<<dim3(32, 4), 256, 0, stream>>>(Ctx, Wb + 3145728, bo, out);
}

// Round 20
// 175.749 us; speedup vs baseline: 1.1788x; 1.1788x over previous
//
#include <hip/hip_runtime.h>

#define D_MODEL 1024
#define T_SEQ   2048
#define BATCH   2
#define HEADS   16
#define DKH     64
#define M_ROWS  (BATCH*T_SEQ)   // 4096
#define OUT0_SZ (M_ROWS*D_MODEL)  // 4194304
#define PSTR    2060              // P-buffer row stride in bf16 (4120B)
#define HSTRIDE (T_SEQ*DKH)       // 131072 elems per head

typedef short bf16x8 __attribute__((ext_vector_type(8)));
typedef float f32x4  __attribute__((ext_vector_type(4)));
typedef unsigned short u16x4 __attribute__((ext_vector_type(4)));

__device__ __forceinline__ unsigned short f2bf(float f) {
    unsigned u = __builtin_bit_cast(unsigned, f);
    u = (u + 0x7fffu + ((u >> 16) & 1u)) >> 16;
    return (unsigned short)u;
}

__device__ __forceinline__ void gload_lds16(const void* g, void* l) {
    __builtin_amdgcn_global_load_lds(
        (const __attribute__((address_space(1))) void*)g,
        (__attribute__((address_space(3))) void*)l, 16, 0, 0);
}

// ---------------- fp32 -> bf16 convert: x + all 4 weights, ONE launch ----------------
__global__ __launch_bounds__(256) void k_cvt_all(const float* __restrict__ x,
                                                 const float* __restrict__ w0,
                                                 const float* __restrict__ w1,
                                                 const float* __restrict__ w2,
                                                 const float* __restrict__ w3,
                                                 unsigned short* __restrict__ xb,
                                                 unsigned short* __restrict__ wb) {
    int blk = blockIdx.x;
    const float* src;
    unsigned short* dst;
    int i;
    if (blk < 4096) {
        src = x; dst = xb; i = blk * 256 + threadIdx.x;
    } else {
        int k = (blk - 4096) >> 10;
        src = (k == 0) ? w0 : (k == 1) ? w1 : (k == 2) ? w2 : w3;
        dst = wb + (size_t)k * 1048576;
        i = ((blk - 4096) & 1023) * 256 + threadIdx.x;
    }
    float4 v = reinterpret_cast<const float4*>(src)[i];
    ushort4 o;
    o.x = f2bf(v.x); o.y = f2bf(v.y); o.z = f2bf(v.z); o.w = f2bf(v.w);
    reinterpret_cast<ushort4*>(dst)[i] = o;
}

// ---------------- shared 128x128 GEMM core (C = A * W^T), K = 1024 ----------------
__device__ __forceinline__ void stage_tile(const unsigned short* __restrict__ g,
                                           int r0, int k0, unsigned short* s, int tid) {
#pragma unroll
    for (int it = 0; it < 4; ++it) {
        int row   = (tid >> 3) + it * 32;
        int kb_sw = (tid & 7) << 4;
        int kb    = kb_sw ^ ((row & 7) << 4);
        const unsigned short* gp = g + (size_t)(r0 + row) * D_MODEL + k0 + (kb >> 1);
        gload_lds16(gp, s + (tid >> 6) * 512 + it * 2048);
    }
}

__device__ __forceinline__ bf16x8 ld_frag(const unsigned short* s, int row, int kbyte) {
    int off = (row << 7) + (kbyte ^ ((row & 7) << 4));
    return *reinterpret_cast<const bf16x8*>(reinterpret_cast<const char*>(s) + off);
}

__device__ __forceinline__ void gemm_core(const unsigned short* __restrict__ A,
                                          const unsigned short* __restrict__ W,
                                          unsigned short* sA, unsigned short* sB,
                                          int m0, int n0, f32x4 (&acc)[4][4], int tid) {
    int lane = tid & 63, lr = lane & 15, lg = lane >> 4;
    int wm = tid >> 7, wn = (tid >> 6) & 1;
#pragma unroll 1
    for (int k0 = 0; k0 < D_MODEL; k0 += 64) {
        stage_tile(A, m0, k0, sA, tid);
        stage_tile(W, n0, k0, sB, tid);
        __syncthreads();
#pragma unroll
        for (int kk = 0; kk < 2; ++kk) {
            bf16x8 a[4], b[4];
#pragma unroll
            for (int f = 0; f < 4; ++f) {
                a[f] = ld_frag(sA, wm * 64 + f * 16 + lr, kk * 64 + lg * 16);
                b[f] = ld_frag(sB, wn * 64 + f * 16 + lr, kk * 64 + lg * 16);
            }
#pragma unroll
            for (int i = 0; i < 4; ++i)
#pragma unroll
                for (int j = 0; j < 4; ++j)
                    acc[i][j] = __builtin_amdgcn_mfma_f32_16x16x32_bf16(a[i], b[j], acc[i][j], 0, 0, 0);
        }
        __syncthreads();
    }
}

// ---------------- QKV projection (Q/K/V all written in MFMA-fragment order) ----------------
__global__ __launch_bounds__(256) void k_gemm_qkv(const unsigned short* __restrict__ Xb,
                                                  const unsigned short* __restrict__ Wb,
                                                  const float* __restrict__ bq,
                                                  const float* __restrict__ bk,
                                                  const float* __restrict__ bv,
                                                  unsigned short* __restrict__ Qb,
                                                  unsigned short* __restrict__ Kb,
                                                  unsigned short* __restrict__ Vt) {
    __shared__ unsigned short sA[128 * 64];
    __shared__ unsigned short sB[128 * 64];
    int tid = threadIdx.x;
    int m0 = blockIdx.x * 128, n0 = blockIdx.y * 128, z = blockIdx.z;
    const unsigned short* W = Wb + (size_t)z * (D_MODEL * D_MODEL);
    const float* bias = (z == 0) ? bq : (z == 1) ? bk : bv;
    f32x4 acc[4][4];
#pragma unroll
    for (int i = 0; i < 4; ++i)
#pragma unroll
        for (int j = 0; j < 4; ++j) acc[i][j] = (f32x4){0.f, 0.f, 0.f, 0.f};

    gemm_core(Xb, W, sA, sB, m0, n0, acc, tid);

    int lane = tid & 63, lr = lane & 15, lg = lane >> 4;
    int wm = tid >> 7, wn = (tid >> 6) & 1;
    float scl = (z == 0) ? 0.125f : 1.0f;   // fold 1/sqrt(64) into Q
#pragma unroll
    for (int i = 0; i < 4; ++i) {
#pragma unroll
        for (int j = 0; j < 4; ++j) {
            int col = n0 + wn * 64 + j * 16 + lr;       // n = h*64 + d
            float bb = bias[col];
            int h = col >> 6, d = col & 63;
#pragma unroll
            for (int q = 0; q < 4; ++q) {
                int row = m0 + wm * 64 + i * 16 + lg * 4 + q;  // b*T + t
                int b = row >> 11, tt = row & 2047;
                float v = (acc[i][j][q] + bb) * scl;
                unsigned short h16 = f2bf(v);
                size_t bh = (size_t)b * HEADS + h;
                if (z == 2) {
                    int st = tt >> 6, ks = (tt >> 5) & 1, lgv = (tt >> 3) & 3, e = tt & 7;
                    Vt[bh * HSTRIDE + st * 4096 + ks * 2048 + lgv * 512 + d * 8 + e] = h16;
                } else if (z == 0) {
                    int ch = tt >> 4, t_in = tt & 15, kk2 = d >> 5, lg8 = (d >> 3) & 3, e = d & 7;
                    Qb[bh * HSTRIDE + ch * 1024 + kk2 * 512 + lg8 * 128 + t_in * 8 + e] = h16;
                } else {
                    int st = tt >> 6, s_in = tt & 63, kk2 = d >> 5, lg8 = (d >> 3) & 3, e = d & 7;
                    Kb[bh * HSTRIDE + st * 4096 + kk2 * 2048 + lg8 * 512 + s_in * 8 + e] = h16;
                }
            }
        }
    }
}

// ---------------- output projection ----------------
__global__ __launch_bounds__(256) void k_gemm_o(const unsigned short* __restrict__ Ctx,
                                                const unsigned short* __restrict__ Wo,
                                                const float* __restrict__ bo,
                                                float* __restrict__ out) {
    __shared__ unsigned short sA[128 * 64];
    __shared__ unsigned short sB[128 * 64];
    int tid = threadIdx.x;
    int m0 = blockIdx.x * 128, n0 = blockIdx.y * 128;
    f32x4 acc[4][4];
#pragma unroll
    for (int i = 0; i < 4; ++i)
#pragma unroll
        for (int j = 0; j < 4; ++j) acc[i][j] = (f32x4){0.f, 0.f, 0.f, 0.f};

    gemm_core(Ctx, Wo, sA, sB, m0, n0, acc, tid);

    int lane = tid & 63, lr = lane & 15, lg = lane >> 4;
    int wm = tid >> 7, wn = (tid >> 6) & 1;
#pragma unroll
    for (int i = 0; i < 4; ++i)
#pragma unroll
        for (int j = 0; j < 4; ++j) {
            int col = n0 + wn * 64 + j * 16 + lr;
            float bb = bo[col];
#pragma unroll
            for (int q = 0; q < 4; ++q) {
                int row = m0 + wm * 64 + i * 16 + lg * 4 + q;
                out[(size_t)row * D_MODEL + col] = acc[i][j][q] + bb;
            }
        }
}

// ---------------- fused causal attention: coalesced fragment loads + NT stores ----------------
// grid (128 chunks of 16 q-rows, B*H); 512 threads, 8 waves.
__global__ __launch_bounds__(512) void k_attn(const unsigned short* __restrict__ Qb,
                                              const unsigned short* __restrict__ Kb,
                                              const unsigned short* __restrict__ Vt,
                                              float* __restrict__ Wout,
                                              unsigned short* __restrict__ Ctx) {
    __shared__ unsigned short P[16 * PSTR];   // 65,920 B
    __shared__ float l8[8][16];
    __shared__ float linv[16];
    int tid = threadIdx.x, w = tid >> 6, lane = tid & 63, lr = lane & 15, lg = lane >> 4;
    int bh = blockIdx.y;
    int b = bh >> 4, h = bh & 15;
    int chunk = (blockIdx.x * 53 + 17) & 127;  // decorrelating bijection
    int t0 = chunk * 16;
    int ntiles = (chunk >> 2) + 1;
    int q_row = t0 + lr;

    const unsigned short* Qh = Qb + (size_t)bh * HSTRIDE;
    const unsigned short* Kh = Kb + (size_t)bh * HSTRIDE;
    const unsigned short* Vh = Vt + (size_t)bh * HSTRIDE;
    float* Whead = Wout + (size_t)bh * T_SEQ * T_SEQ;

    bf16x8 qf[2];
#pragma unroll
    for (int kk = 0; kk < 2; ++kk)
        qf[kk] = *reinterpret_cast<const bf16x8*>(
            Qh + chunk * 1024 + kk * 512 + lg * 128 + lr * 8);

    // ---- phase A: QK^T once (tiles st%8==w), coalesced Kf fragment loads ----
    float lacc = 0.f;
    for (int st = w; st < ntiles; st += 8) {
        int s0 = st * 64;
        bool diag = (st == ntiles - 1);
#pragma unroll
        for (int cf = 0; cf < 4; ++cf) {
            f32x4 a = (f32x4){0.f, 0.f, 0.f, 0.f};
#pragma unroll
            for (int kk = 0; kk < 2; ++kk) {
                bf16x8 kf = *reinterpret_cast<const bf16x8*>(
                    Kh + st * 4096 + kk * 2048 + lg * 512 + (cf * 16 + lr) * 8);
                a = __builtin_amdgcn_mfma_f32_16x16x32_bf16(kf, qf[kk], a, 0, 0, 0);
            }
            u16x4 pb;
#pragma unroll
            for (int r = 0; r < 4; ++r) {
                int s = s0 + cf * 16 + lg * 4 + r;
                float p = (diag && s > q_row) ? 0.f : __expf(a[r] - 16.f);
                lacc += p;
                pb[r] = f2bf(p);
            }
            *reinterpret_cast<u16x4*>(&P[lr * PSTR + s0 + cf * 16 + lg * 4]) = pb;
        }
    }
    lacc += __shfl_xor(lacc, 16);
    lacc += __shfl_xor(lacc, 32);
    l8[w][lr] = lacc;
    __syncthreads();
    if (tid < 16) {
        float s = 0.f;
#pragma unroll
        for (int i = 0; i < 8; ++i) s += l8[i][tid];
        linv[tid] = 1.0f / s;
    }
    __syncthreads();

    if (w < 4) {
        // ===== waves 0-3: PV for d-quarter w over ALL tiles (coalesced Vf) + Ctx =====
        float invq = linv[lr];
        f32x4 of = (f32x4){0.f, 0.f, 0.f, 0.f};
        for (int st = 0; st < ntiles; ++st) {
            int s0 = st * 64;
#pragma unroll
            for (int ks = 0; ks < 2; ++ks) {
                bf16x8 pa = *reinterpret_cast<const bf16x8*>(&P[lr * PSTR + s0 + ks * 32 + lg * 8]);
                bf16x8 vf = *reinterpret_cast<const bf16x8*>(
                    Vh + st * 4096 + ks * 2048 + lg * 512 + (w * 16 + lr) * 8);
                of = __builtin_amdgcn_mfma_f32_16x16x32_bf16(vf, pa, of, 0, 0, 0);
            }
        }
        u16x4 c4;
#pragma unroll
        for (int r = 0; r < 4; ++r) c4[r] = f2bf(of[r] * invq);
        *reinterpret_cast<u16x4*>(
            &Ctx[((size_t)b * T_SEQ + q_row) * D_MODEL + h * DKH + w * 16 + lg * 4]) = c4;
    } else {
        // ===== waves 4-7: NT weight stores, rows (w-4)*4 .. +3, 8KB/row =====
        int vcols = ntiles * 64;
        int wq = w - 4;
#pragma unroll
        for (int rr = 0; rr < 4; ++rr) {
            int row = wq * 4 + rr;
            float invlr = linv[row];
            float* dst = Whead + (size_t)(t0 + row) * T_SEQ;
            const unsigned short* prow = &P[row * PSTR];
#pragma unroll 2
            for (int j = 0; j < 8; ++j) {
                int col = j * 256 + lane * 4;
                f32x4 v = (f32x4){0.f, 0.f, 0.f, 0.f};
                if (col < vcols) {
                    u16x4 pb = *reinterpret_cast<const u16x4*>(&prow[col]);
#pragma unroll
                    for (int r = 0; r < 4; ++r)
                        v[r] = __builtin_bit_cast(float, (unsigned)pb[r] << 16) * invlr;
                }
                __builtin_nontemporal_store(v, reinterpret_cast<f32x4*>(dst + col));
            }
        }
    }
}

extern "C" void kernel_launch(void* const* d_in, const int* in_sizes, int n_in,
                              void* d_out, int out_size, void* d_ws, size_t ws_size,
                              hipStream_t stream) {
    const float* x  = (const float*)d_in[0];
    const float* Wq = (const float*)d_in[1];
    const float* bq = (const float*)d_in[2];
    const float* Wk = (const float*)d_in[3];
    const float* bk = (const float*)d_in[4];
    const float* Wv = (const float*)d_in[5];
    const float* bv = (const float*)d_in[6];
    const float* Wo = (const float*)d_in[7];
    const float* bo = (const float*)d_in[8];
    float* out = (float*)d_out;

    char* ws = (char*)d_ws;
    unsigned short* Xb  = (unsigned short*)(ws);                 // 8 MB
    unsigned short* Wb  = (unsigned short*)(ws + 8388608);       // 8 MB (Wq,Wk,Wv,Wo)
    unsigned short* Qb  = (unsigned short*)(ws + 16777216);      // 8 MB
    unsigned short* Kb  = (unsigned short*)(ws + 25165824);      // 8 MB
    unsigned short* Vt  = (unsigned short*)(ws + 33554432);      // 8 MB
    unsigned short* Ctx = (unsigned short*)(ws + 41943040);      // 8 MB

    // fp32 -> bf16 (x + all weights, one launch)
    k_cvt_all<<<8192, 256, 0, stream>>>(x, Wq, Wk, Wv, Wo, Xb, Wb);

    // QKV projection: grid (M/128, N/128, 3)
    k_gemm_qkv<<<dim3(32, 8, 3), 256, 0, stream>>>(Xb, Wb, bq, bk, bv, Qb, Kb, Vt);

    // fused causal attention (coalesced fragment loads, NT streaming stores)
    k_attn<<<dim3(128, 32), 512, 0, stream>>>(Qb, Kb, Vt, out + OUT0_SZ, Ctx);

    // output projection
    k_gemm_o<<<dim3(32, 8), 256, 0, stream>>>(Ctx, Wb + 3145728, bo, out);
}